// Round 10
// baseline (220.048 us; speedup 1.0000x reference)
//
#include <hip/hip_runtime.h>

// Problem constants (fixed by setup_inputs)
#define HW   256
#define Bb   4
#define Nn   256       // K keypoints (per image batch)
#define Pp   33
#define PPAD 36        // padded patch row (float)
#define OUTF 128
#define SIG  16

// conv1-output plane (bf16 hi only) for MFMA A-operands:
// [rowslot 6][parity 2][col' 16][kc 40 (32 used + 8 pad)] ushort.
#define KCP   40
#define PLROW (2 * 16 * KCP)       // shorts per row-slot = 1280
#define PLSZ  (6 * PLROW)          // 7680 shorts

// ws layout (float offsets)
#define WS_W1T  0        // [27][32] f32 = 864 (tap-major, ch-minor -> s_load_dwordx8-able)
#define WS_BHI  864      // 18432 ushort = 9216 f  (B-frags hi, frag-ordered)
#define WS_BLO  10080    // 18432 ushort = 9216 f  (B-frags lo)
#define WS_WLT  19296    // [64][128] f32 = 8192

typedef __attribute__((ext_vector_type(8))) short v8s;    // 8 bf16 (4 VGPRs)
typedef __attribute__((ext_vector_type(4))) float f32x4;  // MFMA acc

__device__ __forceinline__ unsigned short f2bf_rne(float x) {
  unsigned u = __float_as_uint(x);
  unsigned r = (u + 0x7FFFu + ((u >> 16) & 1u)) >> 16;
  return (unsigned short)r;
}
__device__ __forceinline__ float bf2f(unsigned short h) {
  return __uint_as_float(((unsigned)h) << 16);
}

__global__ __launch_bounds__(256) void prep_kernel(
    const float* __restrict__ w1, const float* __restrict__ w2,
    const float* __restrict__ wl, float* __restrict__ ws,
    float* __restrict__ out) {
  int t = blockIdx.x * 256 + threadIdx.x;
  int stride = gridDim.x * 256;
  if (blockIdx.x == 0 && threadIdx.x == 0) out[0] = 0.0f;
  for (int i = t; i < 864; i += stride) {        // w1t[k27][ch32]
    int ch = i & 31, k = i >> 5;
    ws[WS_W1T + i] = w1[ch * 27 + k];
  }
  // B-fragments for mfma_f32_16x16x32_bf16:
  // element j of lane l, wave w, tap t: n(ch) = w*16 + (l&15), k(kc) = (l>>4)*8 + j
  unsigned short* bhi = (unsigned short*)(ws + WS_BHI);
  unsigned short* blo = (unsigned short*)(ws + WS_BLO);
  for (int i = t; i < 18432; i += stride) {
    int j  = i & 7;
    int l  = (i >> 3) & 63;
    int w  = (i >> 9) & 3;
    int tp = i >> 11;              // 0..8 = ky*3+kx
    int ch = w * 16 + (l & 15);
    int kc = ((l >> 4) << 3) + j;
    int ky = tp / 3, kx = tp - ky * 3;
    float v = w2[ch * 288 + kc * 9 + ky * 3 + kx];
    unsigned short h = f2bf_rne(v);
    bhi[i] = h;
    blo[i] = f2bf_rne(v - bf2f(h));
  }
  for (int i = t; i < 8192; i += stride) {       // wlt[i64][o128]
    int o = i & 127, ii = i >> 7;
    ws[WS_WLT + i] = wl[o * 64 + ii];
  }
}

// One block per (n,b) sample, both sides in-block, one atomicAdd.
// conv1 NEW mapping (R10): lane = rowhalf(2) x col(32)  -> every ds_read_b32 has
// 64 distinct addresses (256 B/instr, the LDS max; 2-way bank = free), wave owns
// a kc-OCTET (wbase = wave*8), weights come via SCALAR loads from ws (uniform
// address via readfirstlane -> s_load, SMEM pipe, zero LDS cost), outputs pack
// to ONE ds_write_b128 per lane. R9's mapping burned ~12k LDS-cyc/wave on
// broadcast-narrow patch reads + per-produce weight reloads.
// conv2 (MFMA, unchanged): wave = ch-tile; A from hiP, B hi/lo from global (L2).
__global__ __launch_bounds__(256) void patch_cnn_kernel(
    const float* __restrict__ imgG, const float* __restrict__ imgS,
    const float* __restrict__ kpG,  const float* __restrict__ kpS,
    const float* __restrict__ b1g,  const float* __restrict__ b2g,
    const float* __restrict__ blg,  const float* __restrict__ ws,
    float* __restrict__ out) {
  __shared__ __align__(16) float patch[3 * Pp * PPAD];     // 14256 B
  __shared__ __align__(16) unsigned short hiP[PLSZ];       // 15360 B
  __shared__ float gapv[64];
  __shared__ float fstash[OUTF];
  __shared__ float lred[4];
  // total ~= 30.4 KB

  const int bid  = blockIdx.x;          // grid 1024
  const int n    = bid >> 2;
  const int b    = bid & 3;
  const int tid  = threadIdx.x;
  const int wave = tid >> 6;
  const int lane = tid & 63;

  // conv1 roles (new)
  const int col   = lane & 31;               // output col 0..31 (31 = pad)
  const int rhalf = lane >> 5;               // row within produced pair
  const int wbase = __builtin_amdgcn_readfirstlane(wave * 8);  // kc octet base
  // conv2 roles (unchanged)
  const int m = lane & 15;
  const int q = lane >> 4;

  const float* __restrict__ w1t = ws + WS_W1T;

  // per-wave conv1 biases (uniform -> s_load)
  float bias1[8];
#pragma unroll
  for (int j = 0; j < 8; ++j) bias1[j] = b1g[wbase + j];

  // per-thread B-frag base pointers (global, L2-resident); frag t at [t*256]
  const v8s* bhW = (const v8s*)((const unsigned short*)(ws + WS_BHI)) +
                   (wave * 64 + lane);
  const v8s* blW = (const v8s*)((const unsigned short*)(ws + WS_BLO)) +
                   (wave * 64 + lane);
  const float b2v = b2g[wave * 16 + m];

  // conv1 producer: rows r0,r0+1 -> plane slots ps,ps+1
  auto produce = [&](int r0, int ps) {
    const int row  = r0 + rhalf;
    const int rowc = min(row, 30);           // clamp load addr (store masked)
    int sl = ps + rhalf; if (sl >= 6) sl -= 6;
    float acc1[8];
#pragma unroll
    for (int j = 0; j < 8; ++j) acc1[j] = bias1[j];
#pragma unroll
    for (int ci = 0; ci < 3; ++ci) {
#pragma unroll
      for (int ky = 0; ky < 3; ++ky) {
        const float* pr = &patch[(ci * Pp + rowc + ky) * PPAD + col];
#pragma unroll
        for (int kx = 0; kx < 3; ++kx) {
          const float v = pr[kx];            // ds_read_b32, 64 distinct addrs
          const int t = (ci * 3 + ky) * 3 + kx;
#pragma unroll
          for (int j = 0; j < 8; ++j)        // weights: uniform -> s_load
            acc1[j] = fmaf(v, w1t[t * 32 + wbase + j], acc1[j]);
        }
      }
    }
    if (row <= 30) {
      v8s hv;
#pragma unroll
      for (int j = 0; j < 8; ++j)
        hv[j] = (short)f2bf_rne(fmaxf(acc1[j], 0.0f));
      const int idx = ((sl * 2 + (col & 1)) * 16 + (col >> 1)) * KCP + wbase;
      *(v8s*)&hiP[idx] = hv;                 // one ds_write_b128
    }
  };

  float dd = 0.0f;

#pragma unroll 1
  for (int side = 0; side < 2; ++side) {
    const float* img = side ? imgS : imgG;
    const float* kp  = side ? kpS : kpG;

    int sx = (int)floorf(kp[n * 2 + 0] * 256.0f) - SIG;
    int sy = (int)floorf(kp[n * 2 + 1] * 256.0f) - SIG;
    sx = min(max(sx, 0), HW - Pp);
    sy = min(max(sy, 0), HW - Pp);

    // stage patch (zero pad cols)
    for (int i = tid; i < 3 * Pp * PPAD; i += 256) {
      int ci = i / (Pp * PPAD);
      int r2 = i - ci * (Pp * PPAD);
      int r  = r2 / PPAD;
      int cc = r2 - r * PPAD;
      float v = 0.0f;
      if (cc < Pp) v = img[((b * 3 + ci) * HW + (sy + r)) * HW + (sx + cc)];
      patch[i] = v;
    }
    __syncthreads();           // patch ready

    float gapAcc = 0.0f;
    produce(0, 0);
    produce(2, 2);

    int s0 = 0;
#pragma unroll 1
    for (int y2 = 0; y2 < 15; ++y2) {
      __syncthreads();         // producer writes visible
      f32x4 acc = {0.f, 0.f, 0.f, 0.f};
#pragma unroll
      for (int ky = 0; ky < 3; ++ky) {
        int sk = s0 + ky; if (sk >= 6) sk -= 6;
#pragma unroll
        for (int kx = 0; kx < 3; ++kx) {
          const int p = kx & 1;
          int cp = m + (kx >> 1); if (cp > 15) cp = 15;
          const int idx = ((sk * 2 + p) * 16 + cp) * KCP + q * 8;
          v8s ah = *(const v8s*)&hiP[idx];
          const int t = ky * 3 + kx;
          v8s bh = bhW[t * 256];       // global, L2-hit
          v8s bl = blW[t * 256];
          acc = __builtin_amdgcn_mfma_f32_16x16x32_bf16(ah, bh, acc, 0, 0, 0);
          acc = __builtin_amdgcn_mfma_f32_16x16x32_bf16(ah, bl, acc, 0, 0, 0);
        }
      }
      {
        float s = fmaxf(acc.x + b2v, 0.f) + fmaxf(acc.y + b2v, 0.f) +
                  fmaxf(acc.z + b2v, 0.f);
        if (q < 3) s += fmaxf(acc.w + b2v, 0.f);   // x=15 row is pad
        gapAcc += s;
      }
      const int r0 = 2 * y2 + 4;
      if (r0 <= 30) {
        int ps = s0 + 4; if (ps >= 6) ps -= 6;
        produce(r0, ps);
      }
      s0 += 2; if (s0 >= 6) s0 -= 6;
    }

    // reduce gapAcc over kc-quads (lanes m, m+16, m+32, m+48)
    gapAcc += __shfl_down(gapAcc, 32, 64);
    gapAcc += __shfl_down(gapAcc, 16, 64);
    if (lane < 16) gapv[wave * 16 + m] = gapAcc * (1.0f / 225.0f);
    __syncthreads();

    if (tid < OUTF) {
      float f = blg[tid];
#pragma unroll 8
      for (int i = 0; i < 64; ++i) f = fmaf(gapv[i], ws[WS_WLT + i * OUTF + tid], f);
      if (side == 0) {
        fstash[tid] = f;
      } else {
        float d = f - fstash[tid];
        dd = d * d;
      }
    }
    __syncthreads();           // fstash/gapv settled before next side reuses LDS
  }

  // block reduction of dd -> one atomicAdd
  dd += __shfl_down(dd, 32, 64);
  dd += __shfl_down(dd, 16, 64);
  dd += __shfl_down(dd, 8, 64);
  dd += __shfl_down(dd, 4, 64);
  dd += __shfl_down(dd, 2, 64);
  dd += __shfl_down(dd, 1, 64);
  if (lane == 0) lred[wave] = dd;
  __syncthreads();
  if (tid == 0) {
    float s = (lred[0] + lred[1]) + (lred[2] + lred[3]);
    atomicAdd(out, s * (1.0f / 131072.0f));
  }
}

extern "C" void kernel_launch(void* const* d_in, const int* in_sizes, int n_in,
                              void* d_out, int out_size, void* d_ws, size_t ws_size,
                              hipStream_t stream) {
  const float* imgG = (const float*)d_in[0];
  const float* imgS = (const float*)d_in[1];
  const float* kpG  = (const float*)d_in[2];
  const float* kpS  = (const float*)d_in[3];
  const float* w1   = (const float*)d_in[4];
  const float* b1   = (const float*)d_in[5];
  const float* w2   = (const float*)d_in[6];
  const float* b2   = (const float*)d_in[7];
  const float* wl   = (const float*)d_in[8];
  const float* bl   = (const float*)d_in[9];
  float* ws  = (float*)d_ws;
  float* out = (float*)d_out;

  hipLaunchKernelGGL(prep_kernel, dim3(32), dim3(256), 0, stream, w1, w2, wl, ws, out);
  hipLaunchKernelGGL(patch_cnn_kernel, dim3(1024), dim3(256), 0, stream,
                     imgG, imgS, kpG, kpS, b1, b2, bl, ws, out);
}

// Round 11
// 152.138 us; speedup vs baseline: 1.4464x; 1.4464x over previous
//
#include <hip/hip_runtime.h>

// Problem constants (fixed by setup_inputs)
#define HW   256
#define Pp   33
#define PPAD 36        // padded patch row (ushort units)
#define OUTF 128
#define SIG  16

// conv1-output plane (bf16) for conv2 MFMA A-operands:
// [rowslot 6][parity 2][col' 16][kc 40] ushort.
#define KCP   40
#define PLROW (2 * 16 * KCP)
#define PLSZ  (6 * PLROW)        // 7680 shorts
#define IMS   40                 // im2col k-stride (shorts); 80B rows, b128-aligned

// ws layout (float offsets)
#define WS_W1FH 0       // [2 nt][64 lane][8 j] ushort = 512 f (conv1 B-frags hi)
#define WS_W1FL 512     // same, lo
#define WS_BHI  1024    // 18432 ushort = 9216 f (conv2 B-frags hi)
#define WS_BLO  10240   // conv2 B-frags lo
#define WS_WLT  19456   // [64][128] f32 = 8192

typedef __attribute__((ext_vector_type(8))) short v8s;    // 8 bf16
typedef __attribute__((ext_vector_type(4))) float f32x4;  // MFMA acc

__device__ __forceinline__ unsigned short f2bf_rne(float x) {
  unsigned u = __float_as_uint(x);
  unsigned r = (u + 0x7FFFu + ((u >> 16) & 1u)) >> 16;
  return (unsigned short)r;
}
__device__ __forceinline__ float bf2f(unsigned short h) {
  return __uint_as_float(((unsigned)h) << 16);
}

__global__ __launch_bounds__(256) void prep_kernel(
    const float* __restrict__ w1, const float* __restrict__ w2,
    const float* __restrict__ wl, float* __restrict__ ws,
    float* __restrict__ out) {
  int t = blockIdx.x * 256 + threadIdx.x;
  int stride = gridDim.x * 256;
  if (blockIdx.x == 0 && threadIdx.x == 0) out[0] = 0.0f;
  // conv1 B-frags: k = 8*(l>>4)+j (27-dim padded to 32), ch = 16*nt + (l&15)
  unsigned short* w1h = (unsigned short*)(ws + WS_W1FH);
  unsigned short* w1lo = (unsigned short*)(ws + WS_W1FL);
  for (int i = t; i < 1024; i += stride) {
    int j  = i & 7;
    int l  = (i >> 3) & 63;
    int nt = i >> 9;
    int k  = 8 * (l >> 4) + j;
    int ch = 16 * nt + (l & 15);
    float v = (k < 27) ? w1[ch * 27 + k] : 0.0f;
    unsigned short h = f2bf_rne(v);
    w1h[i]  = h;
    w1lo[i] = f2bf_rne(v - bf2f(h));
  }
  // conv2 B-frags (unchanged): n(ch)=w*16+(l&15), k(kc)=(l>>4)*8+j, per tap
  unsigned short* bhi = (unsigned short*)(ws + WS_BHI);
  unsigned short* blo = (unsigned short*)(ws + WS_BLO);
  for (int i = t; i < 18432; i += stride) {
    int j  = i & 7;
    int l  = (i >> 3) & 63;
    int w  = (i >> 9) & 3;
    int tp = i >> 11;
    int ch = w * 16 + (l & 15);
    int kc = ((l >> 4) << 3) + j;
    int ky = tp / 3, kx = tp - ky * 3;
    float v = w2[ch * 288 + kc * 9 + ky * 3 + kx];
    unsigned short h = f2bf_rne(v);
    bhi[i] = h;
    blo[i] = f2bf_rne(v - bf2f(h));
  }
  for (int i = t; i < 8192; i += stride) {
    int o = i & 127, ii = i >> 7;
    ws[WS_WLT + i] = wl[o * 64 + ii];
  }
}

// One block per (n,b); both sides in-block; one atomicAdd.
// conv1 NOW ON MFMA: per conv1-row, build im2col tile [32 m][32 k] bf16 in LDS
// (4 ds_read_u16 + 1 ds_write_b64 per thread), then 4 waves = 2 M-tiles x
// 2 N-tiles do A*Bhi + A*Blo (w1 frags persist in 8 VGPRs/lane), bias+relu,
// write hiP. Kills R9/R10's conv1 VALU-FMA *and* the weight-path problem.
// Patch stored bf16 (A hi-only: activation noise GAP-averages; w1 hi+lo:
// systematic). conv2 unchanged from R9.
__global__ __launch_bounds__(256) void patch_cnn_kernel(
    const float* __restrict__ imgG, const float* __restrict__ imgS,
    const float* __restrict__ kpG,  const float* __restrict__ kpS,
    const float* __restrict__ b1g,  const float* __restrict__ b2g,
    const float* __restrict__ blg,  const float* __restrict__ ws,
    float* __restrict__ out) {
  __shared__ __align__(16) unsigned short patch[3 * Pp * PPAD];  // 7128 B
  __shared__ __align__(16) unsigned short imcol[2][32 * IMS];    // 5120 B
  __shared__ __align__(16) unsigned short hiP[PLSZ];             // 15360 B
  __shared__ float gapv[64];
  __shared__ float fstash[OUTF];
  __shared__ float lred[4];
  // total ~= 28.6 KB -> 5 blocks/CU by LDS

  const int bid  = blockIdx.x;          // grid 1024
  const int n    = bid >> 2;
  const int b    = bid & 3;
  const int tid  = threadIdx.x;
  const int wave = tid >> 6;
  const int lane = tid & 63;

  const int m16 = lane & 15;
  const int qq  = lane >> 4;
  const int mt  = wave & 1;             // conv1 M-tile
  const int nt  = wave >> 1;            // conv1 N-tile

  // im2col build roles: thread = m(32) x k-quad(8)
  const int bm = tid & 31;
  const int kq = tid >> 5;
  int  boff[4];
  bool bval[4];
#pragma unroll
  for (int j = 0; j < 4; ++j) {
    int k = 4 * kq + j;
    bval[j] = (k < 27);
    int kk = bval[j] ? k : 0;
    int ci = kk / 9, r2 = kk - ci * 9, ky = r2 / 3, kx = r2 - ky * 3;
    boff[j] = (ci * Pp + ky) * PPAD + bm + kx;    // + r*PPAD at use
  }

  // conv1 B-frags -> registers (8 VGPRs each), bias per lane
  const v8s w1hF = ((const v8s*)((const unsigned short*)(ws + WS_W1FH)))[nt * 64 + lane];
  const v8s w1lF = ((const v8s*)((const unsigned short*)(ws + WS_W1FL)))[nt * 64 + lane];
  const float b1v = b1g[nt * 16 + m16];

  // conv2 frag pointers (global, L2-resident) and bias
  const v8s* bhW = (const v8s*)((const unsigned short*)(ws + WS_BHI)) + (wave * 64 + lane);
  const v8s* blW = (const v8s*)((const unsigned short*)(ws + WS_BLO)) + (wave * 64 + lane);
  const float b2v = b2g[wave * 16 + m16];

  auto build_row = [&](int r, int ibuf) {
    unsigned short h[4];
#pragma unroll
    for (int j = 0; j < 4; ++j)
      h[j] = bval[j] ? patch[boff[j] + r * PPAD] : (unsigned short)0;
    unsigned w0 = (unsigned)h[0] | ((unsigned)h[1] << 16);
    unsigned w1_ = (unsigned)h[2] | ((unsigned)h[3] << 16);
    *(uint2*)&imcol[ibuf][bm * IMS + 4 * kq] = make_uint2(w0, w1_);
  };

  auto conv1_row = [&](int ibuf, int sl) {
    v8s af = *(const v8s*)&imcol[ibuf][(16 * mt + m16) * IMS + 8 * qq];
    f32x4 a1 = {0.f, 0.f, 0.f, 0.f};
    a1 = __builtin_amdgcn_mfma_f32_16x16x32_bf16(af, w1hF, a1, 0, 0, 0);
    a1 = __builtin_amdgcn_mfma_f32_16x16x32_bf16(af, w1lF, a1, 0, 0, 0);
#pragma unroll
    for (int rg = 0; rg < 4; ++rg) {
      int x = 16 * mt + 4 * qq + rg;      // pixel col (x=31 garbage, masked later)
      float f = fmaxf(a1[rg] + b1v, 0.f);
      hiP[((sl * 2 + (x & 1)) * 16 + (x >> 1)) * KCP + 16 * nt + m16] = f2bf_rne(f);
    }
  };

  auto produce_pair = [&](int r0) {
    const int rB = min(r0 + 1, 30);       // row 31 invalid -> dup row 30 (unread slot)
    int s0p = r0 % 6;
    int s1p = s0p + 1; if (s1p >= 6) s1p -= 6;
    __syncthreads();                      // prior imcol reads done; patch ready
    build_row(r0, 0);
    build_row(rB, 1);
    __syncthreads();                      // imcol visible
    conv1_row(0, s0p);
    conv1_row(1, s1p);
  };

  float dd = 0.0f;

#pragma unroll 1
  for (int side = 0; side < 2; ++side) {
    const float* img = side ? imgS : imgG;
    const float* kp  = side ? kpS : kpG;

    int sx = (int)floorf(kp[n * 2 + 0] * 256.0f) - SIG;
    int sy = (int)floorf(kp[n * 2 + 1] * 256.0f) - SIG;
    sx = min(max(sx, 0), HW - Pp);
    sy = min(max(sy, 0), HW - Pp);

    // stage patch as bf16 pairs (coalesced float2 global reads)
    for (int i = tid; i < (3 * Pp * PPAD) / 2; i += 256) {
      int e  = 2 * i;
      int ci = e / (Pp * PPAD);
      int r2 = e - ci * (Pp * PPAD);
      int r  = r2 / PPAD;
      int cc = r2 - r * PPAD;
      float vx = 0.f, vy = 0.f;
      const float* rowp = &img[((b * 3 + ci) * HW + (sy + r)) * HW + sx];
      if (cc < 32) { float2 v = *(const float2*)(rowp + cc); vx = v.x; vy = v.y; }
      else if (cc == 32) { vx = rowp[32]; }
      unsigned pk = (unsigned)f2bf_rne(vx) | ((unsigned)f2bf_rne(vy) << 16);
      *(unsigned*)&patch[e] = pk;
    }
    // produce_pair's leading barrier orders staging -> build
    produce_pair(0);     // rows 0,1 -> slots 0,1
    produce_pair(2);     // rows 2,3 -> slots 2,3

    float gapAcc = 0.0f;
    int s0 = 0;
#pragma unroll 1
    for (int y2 = 0; y2 < 15; ++y2) {
      __syncthreads();   // conv1 hiP writes visible
      f32x4 acc = {0.f, 0.f, 0.f, 0.f};
#pragma unroll
      for (int ky = 0; ky < 3; ++ky) {
        int sk = s0 + ky; if (sk >= 6) sk -= 6;
#pragma unroll
        for (int kx = 0; kx < 3; ++kx) {
          const int p = kx & 1;
          int cp = m16 + (kx >> 1); if (cp > 15) cp = 15;
          const int idx = ((sk * 2 + p) * 16 + cp) * KCP + qq * 8;
          v8s ah = *(const v8s*)&hiP[idx];
          const int tp = ky * 3 + kx;
          v8s bh = bhW[tp * 256];
          v8s bl = blW[tp * 256];
          acc = __builtin_amdgcn_mfma_f32_16x16x32_bf16(ah, bh, acc, 0, 0, 0);
          acc = __builtin_amdgcn_mfma_f32_16x16x32_bf16(ah, bl, acc, 0, 0, 0);
        }
      }
      {
        float s = fmaxf(acc.x + b2v, 0.f) + fmaxf(acc.y + b2v, 0.f) +
                  fmaxf(acc.z + b2v, 0.f);
        if (qq < 3) s += fmaxf(acc.w + b2v, 0.f);   // xout=15 is pad
        gapAcc += s;
      }
      const int r0 = 2 * y2 + 4;
      if (r0 <= 30) produce_pair(r0);
      s0 += 2; if (s0 >= 6) s0 -= 6;
    }

    // reduce gapAcc over kc-quads
    gapAcc += __shfl_down(gapAcc, 32, 64);
    gapAcc += __shfl_down(gapAcc, 16, 64);
    if (lane < 16) gapv[wave * 16 + m16] = gapAcc * (1.0f / 225.0f);
    __syncthreads();

    if (tid < OUTF) {
      float f = blg[tid];
#pragma unroll 8
      for (int i = 0; i < 64; ++i) f = fmaf(gapv[i], ws[WS_WLT + i * OUTF + tid], f);
      if (side == 0) fstash[tid] = f;
      else { float d = f - fstash[tid]; dd = d * d; }
    }
    __syncthreads();
  }

  // block reduction -> one atomicAdd
  dd += __shfl_down(dd, 32, 64);
  dd += __shfl_down(dd, 16, 64);
  dd += __shfl_down(dd, 8, 64);
  dd += __shfl_down(dd, 4, 64);
  dd += __shfl_down(dd, 2, 64);
  dd += __shfl_down(dd, 1, 64);
  if (lane == 0) lred[wave] = dd;
  __syncthreads();
  if (tid == 0) {
    float s = (lred[0] + lred[1]) + (lred[2] + lred[3]);
    atomicAdd(out, s * (1.0f / 131072.0f));
  }
}

extern "C" void kernel_launch(void* const* d_in, const int* in_sizes, int n_in,
                              void* d_out, int out_size, void* d_ws, size_t ws_size,
                              hipStream_t stream) {
  const float* imgG = (const float*)d_in[0];
  const float* imgS = (const float*)d_in[1];
  const float* kpG  = (const float*)d_in[2];
  const float* kpS  = (const float*)d_in[3];
  const float* w1   = (const float*)d_in[4];
  const float* b1   = (const float*)d_in[5];
  const float* w2   = (const float*)d_in[6];
  const float* b2   = (const float*)d_in[7];
  const float* wl   = (const float*)d_in[8];
  const float* bl   = (const float*)d_in[9];
  float* ws  = (float*)d_ws;
  float* out = (float*)d_out;

  hipLaunchKernelGGL(prep_kernel, dim3(32), dim3(256), 0, stream, w1, w2, wl, ws, out);
  hipLaunchKernelGGL(patch_cnn_kernel, dim3(1024), dim3(256), 0, stream,
                     imgG, imgS, kpG, kpS, b1, b2, bl, ws, out);
}